// Round 6
// baseline (239.625 us; speedup 1.0000x reference)
//
#include <hip/hip_runtime.h>
#include <hip/hip_fp16.h>

// InstantNGP hash-grid encoding, fp32 in/out.
// N_POINTS=1048576, N_LEVELS=16, F=2. SIZES[l]=2^(l+1), OFFS[l]=2^(l+1)-2.
// Hash: h = x*(P1*P2*P3) + y*(P2*P3) + z*P3 (mod 2^32).
//
// History: R6 132us (barrier-free lane-q, but BOTH divergent paths issue per
// level-pair). R8 121us (wave-uniform q, single-path, but 2 barriers+transpose
// per iter -> lockstep, >50% slack). R9 122us (level 13->LDS, global gathers
// -33%, occupancy /2: NET 0 -> TA-gather NOT the wall, occupancy NOT binding).
// R10: merge the wins. Levels 0..13 in 128KB fp16 LDS makes lane-slot q=7 the
// ONLY global lane and its branch e-independent: ONE lds-gather block (56/64
// lanes) + ONE global block (8/64 lanes) per point-slot -- no double-path tax
// (R6's waste), no barriers/transpose (R8's lockstep), direct coalesced
// out4[t] stores (WRITE_SIZE must stay 131072KB). 1 block/CU, 16 waves,
// free inter-iteration overlap.

#define BLOCK 1024
#define NBLOCKS 512
#define ITERS 16            // 512*1024*16 = 8388608 = 8*N_POINTS point-slots
#define STAGED_ROWS 32766   // levels 0..13: sum 2^(l+1) = 2^15-2
#define LDS_BYTES 131072

__device__ __forceinline__ float2 ldsRow(const unsigned* lds, unsigned idx) {
    unsigned u = lds[idx];
    __half2 h = *(__half2*)&u;
    return __half22float2(h);
}

// Corner hash sums (h000 + D[c]) and trilinear weights, inline (SROA-safe).
#define PREP(FRES, HARR, WARR) \
    unsigned HARR[8]; float WARR[8]; { \
        const float csx = (px + 1.0f) * (FRES); \
        const float csy = (py + 1.0f) * (FRES); \
        const float csz = (pz + 1.0f) * (FRES); \
        const float cfx = floorf(csx), cfy = floorf(csy), cfz = floorf(csz); \
        const float tx = csx - cfx, ty = csy - cfy, tz = csz - cfz; \
        const unsigned hh = (unsigned)cfx * HA + (unsigned)cfy * HB + (unsigned)cfz * HC; \
        const float ux = 1.0f - tx, uy = 1.0f - ty, uz = 1.0f - tz; \
        WARR[0] = ux*uy*uz; WARR[1] = tx*uy*uz; WARR[2] = ux*ty*uz; WARR[3] = tx*ty*uz; \
        WARR[4] = ux*uy*tz; WARR[5] = tx*uy*tz; WARR[6] = ux*ty*tz; WARR[7] = tx*ty*tz; \
        HARR[0] = hh;           HARR[1] = hh + HA;           \
        HARR[2] = hh + HB;      HARR[3] = hh + HA + HB;      \
        HARR[4] = hh + HC;      HARR[5] = hh + HA + HC;      \
        HARR[6] = hh + HB + HC; HARR[7] = hh + HA + HB + HC; \
    }

#define GATHER_LDS(HARR, WARR, MASK, OFF, O0, O1) \
    { _Pragma("unroll") for (int c = 0; c < 8; ++c) { \
        float2 f = ldsRow(lds_tb, (OFF) + ((HARR[c]) & (MASK))); \
        (O0) += f.x * WARR[c]; (O1) += f.y * WARR[c]; } }

#define GATHER_GBL(HARR, WARR, MASK, OFF, O0, O1) \
    { _Pragma("unroll") for (int c = 0; c < 8; ++c) { \
        float2 f = tb[(OFF) + ((HARR[c]) & (MASK))]; \
        (O0) += f.x * WARR[c]; (O1) += f.y * WARR[c]; } }

__global__ __launch_bounds__(BLOCK) void ngp_encode_kernel(
    const float* __restrict__ coords,
    const float* __restrict__ table,
    float* __restrict__ out)
{
    extern __shared__ unsigned lds_tb[];   // 32766 half2 rows (levels 0..13)

    // ---- stage levels 0..13 as fp16 (float4 = 2 rows) ----
    {
        const float4* __restrict__ t4 = (const float4*)table;
        uint2* __restrict__ l2 = (uint2*)lds_tb;
        for (int r = threadIdx.x; r < STAGED_ROWS / 2; r += BLOCK) {  // 16383
            float4 v = t4[r];
            __half2 a = __floats2half2_rn(v.x, v.y);
            __half2 b = __floats2half2_rn(v.z, v.w);
            uint2 u;
            u.x = *(unsigned*)&a;
            u.y = *(unsigned*)&b;
            l2[r] = u;
        }
    }
    __syncthreads();   // the ONLY barrier in the kernel

    constexpr unsigned P1 = 2654435761u, P2 = 29675113u, P3 = 123456789u;
    constexpr unsigned HA = P1 * P2 * P3;
    constexpr unsigned HB = P2 * P3;
    constexpr unsigned HC = P3;

    const float2* __restrict__ tb = (const float2*)table;
    float4* __restrict__ out4 = (float4*)out;

    // Lane-level slot: lane q computes levels (2q, 2q+1) of point t>>3.
    // q<7: both levels from LDS. q==7: levels 14,15 from global (L2-resident).
    const int q = threadIdx.x & 7;
    const int l0 = 2 * q;
    const unsigned mask0 = (2u << l0) - 1u, off0 = mask0 - 1u;
    const unsigned mask1 = (4u << l0) - 1u, off1 = mask1 - 1u;
    const float fres0 = (l0 < 5) ? (float)(16 << l0) : 512.0f;
    const float fres1 = (l0 < 4) ? (float)(32 << l0) : 512.0f;

    for (int it = 0; it < ITERS; ++it) {
        const int t = (blockIdx.x * ITERS + it) * BLOCK + threadIdx.x;
        const int p = t >> 3;

        const float px = coords[3 * p + 0];
        const float py = coords[3 * p + 1];
        const float pz = coords[3 * p + 2];

        PREP(fres0, h0, w0)
        PREP(fres1, h1, w1)

        float o0 = 0.0f, o1 = 0.0f, o2 = 0.0f, o3 = 0.0f;
        if (q != 7) {
            GATHER_LDS(h0, w0, mask0, off0, o0, o1)
            GATHER_LDS(h1, w1, mask1, off1, o2, o3)
        } else {
            GATHER_GBL(h0, w0, mask0, off0, o0, o1)
            GATHER_GBL(h1, w1, mask1, off1, o2, o3)
        }

        // threads t..t+63 write 1KB contiguous: fully coalesced, whole lines.
        out4[t] = make_float4(o0, o1, o2, o3);
    }
}

extern "C" void kernel_launch(void* const* d_in, const int* in_sizes, int n_in,
                              void* d_out, int out_size, void* d_ws, size_t ws_size,
                              hipStream_t stream) {
    const float* coords = (const float*)d_in[0];
    const float* table  = (const float*)d_in[1];
    float* out = (float*)d_out;

    hipFuncSetAttribute((const void*)ngp_encode_kernel,
                        hipFuncAttributeMaxDynamicSharedMemorySize,
                        LDS_BYTES);

    ngp_encode_kernel<<<NBLOCKS, BLOCK, LDS_BYTES, stream>>>(coords, table, out);
}

// Round 7
// 228.593 us; speedup vs baseline: 1.0483x; 1.0483x over previous
//
#include <hip/hip_runtime.h>
#include <hip/hip_fp16.h>

// InstantNGP hash-grid encoding, fp32 in/out.
// N_POINTS=1048576, N_LEVELS=16, F=2. SIZES[l]=2^(l+1), OFFS[l]=2^(l+1)-2.
// Hash: h = x*(P1*P2*P3) + y*(P2*P3) + z*P3 (mod 2^32).
//
// History: R6/R10 132us (lane-q: divergent branch -> BOTH gather paths issue
// per wave, VALU 34%, conflicts 2e7). R8 121us (wave-uniform q: single path,
// VALU 25%, conflicts 4.5e6; residual = transpose lockstep, 2 barriers x 16
// iters). R9: 1 block/CU proven neutral vs 2.
// R11: R8 + de-lockstep. 256-pt iterations (8 barriers/block instead of 32)
// + double-buffered transpose (2x32KB): iter k writes buf[k&1], stores iter
// k-1 from buf[(k-1)&1] -- different buffers, so ONE barrier per iter and
// stores decoupled from same-iter compute. Table levels 0..12 (64KB fp16),
// global levels 13..15 on waves q=0,1,2 with loads issued early into regs.
// LDS 128KB -> 1 block/CU, 16 waves.

#define BLOCK 1024
#define NBLOCKS 512
#define ITERS 8             // 256 points per block-iter; 512*8*256 = 1048576
#define STAGED_ROWS 16382   // levels 0..12: sum 2^(l+1) = 2^14-2
#define TBL_LDS_BYTES 65536
#define BUF_F2 4096         // 16 levels x 256 points per buffer
#define LDS_BYTES (TBL_LDS_BYTES + 2 * BUF_F2 * 8)   // 131072

__device__ __forceinline__ float2 ldsRow(const unsigned* lds, unsigned idx) {
    unsigned u = lds[idx];
    __half2 h = *(__half2*)&u;
    return __half22float2(h);
}

// Corner hash sums (h000 + D[c]) and trilinear weights, inline (SROA-safe).
#define PREP(FRES, HARR, WARR) \
    unsigned HARR[8]; float WARR[8]; { \
        const float csx = (px + 1.0f) * (FRES); \
        const float csy = (py + 1.0f) * (FRES); \
        const float csz = (pz + 1.0f) * (FRES); \
        const float cfx = floorf(csx), cfy = floorf(csy), cfz = floorf(csz); \
        const float tx = csx - cfx, ty = csy - cfy, tz = csz - cfz; \
        const unsigned hh = (unsigned)cfx * HA + (unsigned)cfy * HB + (unsigned)cfz * HC; \
        const float ux = 1.0f - tx, uy = 1.0f - ty, uz = 1.0f - tz; \
        WARR[0] = ux*uy*uz; WARR[1] = tx*uy*uz; WARR[2] = ux*ty*uz; WARR[3] = tx*ty*uz; \
        WARR[4] = ux*uy*tz; WARR[5] = tx*uy*tz; WARR[6] = ux*ty*tz; WARR[7] = tx*ty*tz; \
        HARR[0] = hh;           HARR[1] = hh + HA;           \
        HARR[2] = hh + HB;      HARR[3] = hh + HA + HB;      \
        HARR[4] = hh + HC;      HARR[5] = hh + HA + HC;      \
        HARR[6] = hh + HB + HC; HARR[7] = hh + HA + HB + HC; \
    }

#define GATHER_LDS(HARR, WARR, MASK, OFF, O0, O1) \
    { _Pragma("unroll") for (int c = 0; c < 8; ++c) { \
        float2 f = ldsRow(lds_tb, (OFF) + ((HARR[c]) & (MASK))); \
        (O0) += f.x * WARR[c]; (O1) += f.y * WARR[c]; } }

__global__ __launch_bounds__(BLOCK) void ngp_encode_kernel(
    const float* __restrict__ coords,
    const float* __restrict__ table,
    float* __restrict__ out)
{
    extern __shared__ unsigned char lds_raw[];
    unsigned* lds_tb = (unsigned*)lds_raw;                   // 16382 half2 rows
    float2* lds_buf = (float2*)(lds_raw + TBL_LDS_BYTES);    // 2 x [16][256]

    // ---- stage levels 0..12 as fp16 (float4 = 2 rows) ----
    {
        const float4* __restrict__ t4 = (const float4*)table;
        uint2* __restrict__ l2 = (uint2*)lds_tb;
        for (int r = threadIdx.x; r < STAGED_ROWS / 2; r += BLOCK) {  // 8191
            float4 v = t4[r];
            __half2 a = __floats2half2_rn(v.x, v.y);
            __half2 b = __floats2half2_rn(v.z, v.w);
            uint2 u;
            u.x = *(unsigned*)&a;
            u.y = *(unsigned*)&b;
            l2[r] = u;
        }
    }
    __syncthreads();

    constexpr unsigned P1 = 2654435761u, P2 = 29675113u, P3 = 123456789u;
    constexpr unsigned HA = P1 * P2 * P3;
    constexpr unsigned HB = P2 * P3;
    constexpr unsigned HC = P3;

    const float2* __restrict__ tb = (const float2*)table;
    float4* __restrict__ out4 = (float4*)out;

    // Wave-uniform level assignment: wave q owns levels (q, 15-q).
    // Global path only for lB in {15,14,13} (q<3); levels 0..12 from LDS.
    const int wv   = __builtin_amdgcn_readfirstlane((int)(threadIdx.x >> 6));
    const int q    = wv & 7;
    const int g    = wv >> 3;           // point-group 0/1
    const int lane = threadIdx.x & 63;
    const int plb  = g * 64 + lane;     // local point 0..127 (and +128)

    const int lA = q;
    const int lB = 15 - q;
    const unsigned maskA = (2u << lA) - 1u, offA = maskA - 1u;
    const unsigned maskB = (2u << lB) - 1u, offB = maskB - 1u;
    const unsigned xA = (unsigned)(lA & 14), xB = (unsigned)(lB & 14);

    for (int it = 0; it < ITERS; ++it) {
        const int pbase = blockIdx.x * (ITERS * 256) + it * 256;
        float2* bufW = lds_buf + (it & 1) * BUF_F2;

        // ---- compute 2 points (plb, plb+128), write into bufW ----
#pragma unroll
        for (int half = 0; half < 2; ++half) {
            const int pl = plb + half * 128;
            const int p = pbase + pl;
            const float px = coords[3 * p + 0];
            const float py = coords[3 * p + 1];
            const float pz = coords[3 * p + 2];

            float oA0 = 0.0f, oA1 = 0.0f, oB0 = 0.0f, oB1 = 0.0f;

            if (q < 3) {
                // lB in {15,14,13}: issue 8 global gathers into regs first,
                // run the cheap LDS level, accumulate after (late vmcnt).
                PREP(512.0f, hB, wB)
                float2 gf0 = tb[offB + ((hB[0]) & maskB)];
                float2 gf1 = tb[offB + ((hB[1]) & maskB)];
                float2 gf2 = tb[offB + ((hB[2]) & maskB)];
                float2 gf3 = tb[offB + ((hB[3]) & maskB)];
                float2 gf4 = tb[offB + ((hB[4]) & maskB)];
                float2 gf5 = tb[offB + ((hB[5]) & maskB)];
                float2 gf6 = tb[offB + ((hB[6]) & maskB)];
                float2 gf7 = tb[offB + ((hB[7]) & maskB)];
                {
                    const float fresA = (float)(16 << lA);
                    PREP(fresA, hA, wA)
                    GATHER_LDS(hA, wA, maskA, offA, oA0, oA1)
                }
                oB0 += gf0.x * wB[0]; oB1 += gf0.y * wB[0];
                oB0 += gf1.x * wB[1]; oB1 += gf1.y * wB[1];
                oB0 += gf2.x * wB[2]; oB1 += gf2.y * wB[2];
                oB0 += gf3.x * wB[3]; oB1 += gf3.y * wB[3];
                oB0 += gf4.x * wB[4]; oB1 += gf4.y * wB[4];
                oB0 += gf5.x * wB[5]; oB1 += gf5.y * wB[5];
                oB0 += gf6.x * wB[6]; oB1 += gf6.y * wB[6];
                oB0 += gf7.x * wB[7]; oB1 += gf7.y * wB[7];
            } else if (q < 5) {
                // lA in {3,4} + lB in {12,11} LDS: two preps.
                {
                    const float fresA = (float)(16 << lA);
                    PREP(fresA, hA, wA)
                    GATHER_LDS(hA, wA, maskA, offA, oA0, oA1)
                }
                {
                    PREP(512.0f, hB, wB)
                    GATHER_LDS(hB, wB, maskB, offB, oB0, oB1)
                }
            } else {
                // q=5,6,7: levels (5,10),(6,9),(7,8) -- all res 512, one prep.
                PREP(512.0f, hc, wc)
                GATHER_LDS(hc, wc, maskA, offA, oA0, oA1)
                GATHER_LDS(hc, wc, maskB, offB, oB0, oB1)
            }

            bufW[lA * 256 + (pl ^ xA)] = make_float2(oA0, oA1);
            bufW[lB * 256 + (pl ^ xB)] = make_float2(oB0, oB1);
        }

        // ---- store PREVIOUS iter from the other buffer (no hazard) ----
        if (it > 0) {
            const int sbase = pbase - 256;
            const float2* bufR = lds_buf + ((it - 1) & 1) * BUF_F2;
            const int j  = threadIdx.x;
            const int lp = j >> 3, qq = j & 7;
            const unsigned xr = (unsigned)((2 * qq) & 14);
#pragma unroll
            for (int half = 0; half < 2; ++half) {
                const int lpp = lp + half * 128;
                float2 a = bufR[(2 * qq + 0) * 256 + (lpp ^ xr)];
                float2 b = bufR[(2 * qq + 1) * 256 + (lpp ^ xr)];
                out4[(size_t)(sbase + lpp) * 8 + qq] = make_float4(a.x, a.y, b.x, b.y);
            }
        }

        __syncthreads();   // gates next iter's reuse of buf[(it+1)&1]
    }

    // ---- store final iter ----
    {
        const int sbase = blockIdx.x * (ITERS * 256) + (ITERS - 1) * 256;
        const float2* bufR = lds_buf + ((ITERS - 1) & 1) * BUF_F2;
        const int j  = threadIdx.x;
        const int lp = j >> 3, qq = j & 7;
        const unsigned xr = (unsigned)((2 * qq) & 14);
#pragma unroll
        for (int half = 0; half < 2; ++half) {
            const int lpp = lp + half * 128;
            float2 a = bufR[(2 * qq + 0) * 256 + (lpp ^ xr)];
            float2 b = bufR[(2 * qq + 1) * 256 + (lpp ^ xr)];
            out4[(size_t)(sbase + lpp) * 8 + qq] = make_float4(a.x, a.y, b.x, b.y);
        }
    }
}

extern "C" void kernel_launch(void* const* d_in, const int* in_sizes, int n_in,
                              void* d_out, int out_size, void* d_ws, size_t ws_size,
                              hipStream_t stream) {
    const float* coords = (const float*)d_in[0];
    const float* table  = (const float*)d_in[1];
    float* out = (float*)d_out;

    hipFuncSetAttribute((const void*)ngp_encode_kernel,
                        hipFuncAttributeMaxDynamicSharedMemorySize,
                        LDS_BYTES);

    ngp_encode_kernel<<<NBLOCKS, BLOCK, LDS_BYTES, stream>>>(coords, table, out);
}